// Round 10
// baseline (466.232 us; speedup 1.0000x reference)
//
#include <hip/hip_runtime.h>
#include <stddef.h>

typedef _Float16 half8 __attribute__((ext_vector_type(8)));
typedef float floatx4 __attribute__((ext_vector_type(4)));
typedef float float4v __attribute__((ext_vector_type(4)));

#define NR 8192      // rows (fmap1)
#define MC 8192      // cols (fmap2 rows)
#define KD 256       // feature dim
#define BM 128
#define BN 128
#define KH 128       // K half staged per phase
#define LOGIT_SCALE 0.0625f   // 1/sqrt(256)

// ---------------------------------------------------------------------------
// f32 -> f16 convert (both inputs) + zero rowsum accumulator
// ---------------------------------------------------------------------------
__global__ void convert_kernel(const float* __restrict__ f1, const float* __restrict__ f2,
                               _Float16* __restrict__ h1, _Float16* __restrict__ h2,
                               float* __restrict__ rowsum) {
    int t = blockIdx.x * 256 + threadIdx.x;       // 0 .. 524287
    if (blockIdx.x < 32) rowsum[blockIdx.x * 256 + threadIdx.x] = 0.0f;
    int arr = t >> 18;                            // 262144 threads per array
    int idx = (t & 262143) * 8;
    const float* src = arr ? f2 : f1;
    _Float16* dst = arr ? h2 : h1;
    float4v a = *(const float4v*)(src + idx);
    float4v b = *(const float4v*)(src + idx + 4);
    half8 h;
    h[0] = (_Float16)a[0]; h[1] = (_Float16)a[1];
    h[2] = (_Float16)a[2]; h[3] = (_Float16)a[3];
    h[4] = (_Float16)b[0]; h[5] = (_Float16)b[1];
    h[6] = (_Float16)b[2]; h[7] = (_Float16)b[3];
    *(half8*)(dst + idx) = h;
}

// ---------------------------------------------------------------------------
// Full-K-in-LDS GEMM: stage ALL of K (256) for the 128x128 tile, in 2 halves.
//   stage(h0) -> barrier -> issue stage(h1) + compute(h0) -> barrier
//   -> compute(h1) -> epilogue.   Only 2 barriers per block, no K-loop drain.
// LDS = 128 KiB (1 block/CU). Write-once regions => race-free by construction.
// T2 bank-swizzle: physical slot = (ks&8) | ((ks^row)&7); applied on BOTH the
// global_load_lds source (de-swizzle) and the ds_read address (rule #21).
//   bank-check: lanes 0-15 read rows r..r+15 at same ks; pslot low-3 varies
//   with row => 8 distinct bank-quads, 2-way aliasing only (free per m136).
// MODE 0: accumulate row-wise sum(exp(logit)) into rowsum[] via atomicAdd
// MODE 1: write exp(logit) * (1/rowsum[row]) to out[]
// ---------------------------------------------------------------------------
template <int MODE>
__launch_bounds__(256, 1)
__global__ void corr_gemm(const _Float16* __restrict__ A, const _Float16* __restrict__ B,
                          float* __restrict__ rowsum, float* __restrict__ out) {
    __shared__ __align__(16) _Float16 As[2][BM * KH];   // 2 x 32 KiB
    __shared__ __align__(16) _Float16 Bs[2][BN * KH];   // 2 x 32 KiB

    const int tid  = threadIdx.x;
    const int lane = tid & 63;
    const int wid  = tid >> 6;
    const int wr   = wid >> 1;          // wave row (0..1)  -> 64 rows
    const int wc   = wid & 1;           // wave col (0..1)  -> 64 cols

    // XCD-aware swizzle (4096 blocks, divisible by 8); within an XCD: tn-inner
    // (8 wide) x tm-outer raster -> each XCD holds a 512 KB B-panel in L2.
    int bid = blockIdx.x;
    int swz = (bid & 7) * 512 + (bid >> 3);
    int tn = (swz >> 9) * 8 + (swz & 7);   // 0..63
    int tm = (swz & 511) >> 3;             // 0..63

    const _Float16* Abase = A + (size_t)(tm * BM) * KD;
    const _Float16* Bbase = B + (size_t)(tn * BN) * KD;

    // ---- stage one K-half (128 rows x 128 k) of A and B ----
    // chunk L (16B): LDS row = L>>4, physical slot = L&15.
    // logical k-slot = (pslot&8) | ((pslot^row)&7)  (involution on low 3 bits)
    auto stage = [&](int h) {
#pragma unroll
        for (int m = 0; m < 2; ++m) {
            const _Float16* src = m ? Bbase : Abase;
            _Float16* lbase = m ? &Bs[h][0] : &As[h][0];
#pragma unroll
            for (int i = 0; i < 8; ++i) {
                int L = i * 256 + tid;              // 0..2047 : 16B chunk index
                int row   = L >> 4;                 // 0..127
                int pslot = L & 15;                 // physical 16B slot in row
                int kslot = (pslot & 8) | ((pslot ^ row) & 7);
                const _Float16* g = src + row * KD + h * KH + kslot * 8;
                // wave-uniform LDS base; HW adds lane*16B -> chunk L at L*16B
                _Float16* l = lbase + (size_t)(i * 256 + wid * 64) * 8;
                __builtin_amdgcn_global_load_lds(
                    (const __attribute__((address_space(1))) void*)g,
                    (__attribute__((address_space(3))) void*)l, 16, 0, 0);
            }
        }
    };

    floatx4 acc[4][4];
#pragma unroll
    for (int i = 0; i < 4; ++i)
#pragma unroll
        for (int j = 0; j < 4; ++j) acc[i][j] = floatx4{0.f, 0.f, 0.f, 0.f};

    // ---- compute one staged K-half: 4 kc x (8 ds_read_b128 + 16 MFMA) ----
    auto compute = [&](int h) {
#pragma unroll
        for (int kc = 0; kc < 4; ++kc) {
            half8 af[4], bf[4];
            int ks = kc * 4 + (lane >> 4);          // 0..15
#pragma unroll
            for (int f = 0; f < 4; ++f) {
                int rowA = wr * 64 + f * 16 + (lane & 15);
                int psA  = (ks & 8) | ((ks ^ rowA) & 7);
                af[f] = *(const half8*)(&As[h][rowA * KH + psA * 8]);
                int rowB = wc * 64 + f * 16 + (lane & 15);
                int psB  = (ks & 8) | ((ks ^ rowB) & 7);
                bf[f] = *(const half8*)(&Bs[h][rowB * KH + psB * 8]);
            }
#pragma unroll
            for (int i = 0; i < 4; ++i)
#pragma unroll
                for (int j = 0; j < 4; ++j)
                    acc[i][j] = __builtin_amdgcn_mfma_f32_16x16x32_f16(af[i], bf[j], acc[i][j], 0, 0, 0);
        }
    };

    stage(0);
    __syncthreads();        // half 0 staged (drains vmcnt)
    stage(1);               // half-1 DMA overlaps half-0 compute
    compute(0);
    __syncthreads();        // half 1 staged
    compute(1);

    // ---- epilogue ----
    // C/D layout (m89-verified): col = lane&15, row = (lane>>4)*4 + reg
    if (MODE == 0) {
#pragma unroll
        for (int i = 0; i < 4; ++i) {
#pragma unroll
            for (int r = 0; r < 4; ++r) {
                float s = 0.f;
#pragma unroll
                for (int j = 0; j < 4; ++j) s += __expf(acc[i][j][r] * LOGIT_SCALE);
                // butterfly over the 16 col-lanes (xor bits 0-3 keep lane>>4)
                s += __shfl_xor(s, 1);
                s += __shfl_xor(s, 2);
                s += __shfl_xor(s, 4);
                s += __shfl_xor(s, 8);
                if ((lane & 15) == 0) {
                    int row = tm * BM + wr * 64 + i * 16 + (lane >> 4) * 4 + r;
                    atomicAdd(&rowsum[row], s);
                }
            }
        }
    } else {
#pragma unroll
        for (int i = 0; i < 4; ++i) {
#pragma unroll
            for (int r = 0; r < 4; ++r) {
                int row = tm * BM + wr * 64 + i * 16 + (lane >> 4) * 4 + r;
                float rinv = 1.0f / rowsum[row];
                float* orow = out + (size_t)row * MC + tn * BN + wc * 64 + (lane & 15);
#pragma unroll
                for (int j = 0; j < 4; ++j)
                    orow[j * 16] = __expf(acc[i][j][r] * LOGIT_SCALE) * rinv;
            }
        }
    }
}

// ---------------------------------------------------------------------------
extern "C" void kernel_launch(void* const* d_in, const int* in_sizes, int n_in,
                              void* d_out, int out_size, void* d_ws, size_t ws_size,
                              hipStream_t stream) {
    const float* f1 = (const float*)d_in[0];   // fmap1: 8192x256 f32
    const float* f2 = (const float*)d_in[1];   // fmap2: 8192x256 f32
    float* out = (float*)d_out;                // 8192x8192 f32

    // workspace layout: fmap1_h (4MB) | fmap2_h (4MB) | rowsum (32KB)
    _Float16* h1 = (_Float16*)d_ws;
    _Float16* h2 = h1 + (size_t)NR * KD;
    float* rowsum = (float*)(h2 + (size_t)MC * KD);

    convert_kernel<<<2048, 256, 0, stream>>>(f1, f2, h1, h2, rowsum);
    corr_gemm<0><<<4096, 256, 0, stream>>>(h1, h2, rowsum, nullptr);
    corr_gemm<1><<<4096, 256, 0, stream>>>(h1, h2, rowsum, out);
}